// Round 1
// baseline (11187.164 us; speedup 1.0000x reference)
//
#include <hip/hip_runtime.h>
#include <cstddef>

#define Bc    4096
#define Tc    256
#define CONDc 128
#define INTVc 64
#define Hc    256
#define RB    16      // rows per block in GRU kernel
#define HPAD  260     // padded row stride for h tile (multiple of 4 for float4, breaks 256-stride bank aliasing)

// ---------------------------------------------------------------------------
// Kernel A: seq-feature MLP + h0 projection. One block per batch row.
// ---------------------------------------------------------------------------
__global__ __launch_bounds__(256) void setup_kernel(
    const float* __restrict__ cond, const float* __restrict__ ivf,
    const float* __restrict__ w1, const float* __restrict__ b1,
    const float* __restrict__ w2, const float* __restrict__ b2,
    const float* __restrict__ w3, const float* __restrict__ b3,
    const float* __restrict__ wh0, const float* __restrict__ bh0,
    float* __restrict__ h0out)
{
    __shared__ float iv[INTVc];
    __shared__ float cnd[CONDc];
    __shared__ float s1[2 * INTVc];
    __shared__ float s2[2 * INTVc];
    __shared__ float emb[INTVc];

    const int t = threadIdx.x;
    const int b = blockIdx.x;

    if (t < INTVc) iv[t] = ivf[b * INTVc + t];
    if (t >= 64 && t < 64 + CONDc) cnd[t - 64] = cond[b * CONDc + (t - 64)];
    __syncthreads();

    if (t < 128) {
        float a = b1[t];
        #pragma unroll
        for (int k = 0; k < 64; ++k) a = fmaf(iv[k], w1[k * 128 + t], a);
        s1[t] = fmaxf(a, 0.f);
    }
    __syncthreads();

    if (t < 128) {
        float a = b2[t];
        #pragma unroll
        for (int k = 0; k < 128; ++k) a = fmaf(s1[k], w2[k * 128 + t], a);
        s2[t] = fmaxf(a, 0.f);
    }
    __syncthreads();

    if (t < 64) {
        float a = b3[t];
        #pragma unroll
        for (int k = 0; k < 128; ++k) a = fmaf(s2[k], w3[k * 64 + t], a);
        emb[t] = a;
    }
    __syncthreads();

    {
        float a = bh0[t];
        #pragma unroll 4
        for (int k = 0; k < 128; ++k) a = fmaf(cnd[k], wh0[k * 256 + t], a);
        #pragma unroll 4
        for (int k = 0; k < 64; ++k) a = fmaf(emb[k], wh0[(128 + k) * 256 + t], a);
        h0out[b * 256 + t] = tanhf(a);
    }
}

// ---------------------------------------------------------------------------
// Kernel B: 257-step GRU scan. 16 rows per block, thread t owns hidden unit t
// (gh columns t, t+256, t+512 = gates r,z,n of unit t -> update is thread-local).
// No grid sync needed: rows are independent across the whole scan.
// ---------------------------------------------------------------------------
__global__ __launch_bounds__(256) void gru_kernel(
    const float* __restrict__ times,
    const float* __restrict__ h0,
    const float* __restrict__ w_ih, const float* __restrict__ b_ih,
    const float* __restrict__ w_hh, const float* __restrict__ b_hh,
    const float* __restrict__ w_head, const float* __restrict__ b_head,
    float* __restrict__ out)
{
    __shared__ float h[RB][HPAD];
    __shared__ float xs[RB][257];

    const int t = threadIdx.x;          // hidden unit owned by this thread
    const int row0 = blockIdx.x * RB;

    // stage h0 tile
    #pragma unroll
    for (int r = 0; r < RB; ++r) h[r][t] = h0[(size_t)(row0 + r) * Hc + t];

    // stage per-step scalar inputs: xs[r][0]=0; xs[r][i] = times[i-1]-times[i-2]
    for (int r = 0; r < RB; ++r) {
        for (int i = t; i < 257; i += 256) {
            float x = 0.f;
            if (i >= 1) {
                float a  = times[(size_t)(row0 + r) * Tc + (i - 1)];
                float b2_ = (i >= 2) ? times[(size_t)(row0 + r) * Tc + (i - 2)] : 0.f;
                x = a - b2_;
            }
            xs[r][i] = x;
        }
    }

    // per-thread constants
    const float wi_r = w_ih[t], wi_z = w_ih[256 + t], wi_n = w_ih[512 + t];
    const float br  = b_ih[t]        + b_hh[t];
    const float bz  = b_ih[256 + t]  + b_hh[256 + t];
    const float bin = b_ih[512 + t];
    const float bhn = b_hh[512 + t];
    const float bhead0 = b_head[0], bhead1 = b_head[1];

    __syncthreads();

    for (int step = 0; step < 257; ++step) {
        float accr[RB], accz[RB], accn[RB];
        #pragma unroll
        for (int r = 0; r < RB; ++r) { accr[r] = 0.f; accz[r] = 0.f; accn[r] = 0.f; }

        // gh = h @ w_hh : k-outer, 3 coalesced weight loads per k, LDS broadcast h
        for (int k4 = 0; k4 < Hc / 4; ++k4) {
            const int kb = k4 * 4;
            float wr[4], wz[4], wn[4];
            #pragma unroll
            for (int kk = 0; kk < 4; ++kk) {
                const size_t base = (size_t)(kb + kk) * 768;
                wr[kk] = w_hh[base + t];
                wz[kk] = w_hh[base + 256 + t];
                wn[kk] = w_hh[base + 512 + t];
            }
            #pragma unroll
            for (int rg = 0; rg < 2; ++rg) {
                float4 hv[8];
                #pragma unroll
                for (int r = 0; r < 8; ++r)
                    hv[r] = *(const float4*)(&h[rg * 8 + r][kb]);
                #pragma unroll
                for (int r = 0; r < 8; ++r) {
                    const int rr = rg * 8 + r;
                    const float* hp = (const float*)&hv[r];
                    #pragma unroll
                    for (int kk = 0; kk < 4; ++kk) {
                        accr[rr] = fmaf(hp[kk], wr[kk], accr[rr]);
                        accz[rr] = fmaf(hp[kk], wz[kk], accz[rr]);
                        accn[rr] = fmaf(hp[kk], wn[kk], accn[rr]);
                    }
                }
            }
        }

        __syncthreads();   // all matmul reads of h done before overwriting

        #pragma unroll
        for (int r = 0; r < RB; ++r) {
            const float x  = xs[r][step];
            const float ho = h[r][t];
            const float rg = 1.f / (1.f + __expf(-(fmaf(x, wi_r, br) + accr[r])));
            const float zg = 1.f / (1.f + __expf(-(fmaf(x, wi_z, bz) + accz[r])));
            const float ng = tanhf(fmaf(x, wi_n, bin) + rg * (accn[r] + bhn));
            h[r][t] = (1.f - zg) * ng + zg * ho;
        }

        __syncthreads();   // h_new visible to head + next step

        // head: 32 threads compute the 2*RB outputs for this step
        if (t < 2 * RB) {
            const int r = t >> 1;
            const int c = t & 1;
            float acc = c ? bhead1 : bhead0;
            #pragma unroll 4
            for (int k4 = 0; k4 < Hc / 4; ++k4) {
                const float4 hv = *(const float4*)(&h[r][k4 * 4]);
                acc = fmaf(hv.x, w_head[(k4 * 4 + 0) * 2 + c], acc);
                acc = fmaf(hv.y, w_head[(k4 * 4 + 1) * 2 + c], acc);
                acc = fmaf(hv.z, w_head[(k4 * 4 + 2) * 2 + c], acc);
                acc = fmaf(hv.w, w_head[(k4 * 4 + 3) * 2 + c], acc);
            }
            out[(c ? (size_t)Bc * 257 : 0) + (size_t)(row0 + r) * 257 + step] = acc;
        }
        // no barrier needed here: next writes to h happen only after the
        // next iteration's post-matmul __syncthreads()
    }
}

// ---------------------------------------------------------------------------
extern "C" void kernel_launch(void* const* d_in, const int* in_sizes, int n_in,
                              void* d_out, int out_size, void* d_ws, size_t ws_size,
                              hipStream_t stream) {
    const float* cond   = (const float*)d_in[0];
    const float* ivf    = (const float*)d_in[1];
    const float* times  = (const float*)d_in[2];
    // d_in[3] = seq_lens (unused by reference)
    const float* w1     = (const float*)d_in[4];
    const float* b1     = (const float*)d_in[5];
    const float* w2     = (const float*)d_in[6];
    const float* b2     = (const float*)d_in[7];
    const float* w3     = (const float*)d_in[8];
    const float* b3     = (const float*)d_in[9];
    const float* wh0    = (const float*)d_in[10];
    const float* bh0    = (const float*)d_in[11];
    const float* w_ih   = (const float*)d_in[12];
    const float* b_ih   = (const float*)d_in[13];
    const float* w_hh   = (const float*)d_in[14];
    const float* b_hh   = (const float*)d_in[15];
    const float* w_head = (const float*)d_in[16];
    const float* b_head = (const float*)d_in[17];

    float* outp = (float*)d_out;
    float* h0   = (float*)d_ws;      // B*H floats = 4 MB scratch

    setup_kernel<<<Bc, 256, 0, stream>>>(cond, ivf, w1, b1, w2, b2, w3, b3,
                                         wh0, bh0, h0);
    gru_kernel<<<Bc / RB, 256, 0, stream>>>(times, h0, w_ih, b_ih, w_hh, b_hh,
                                            w_head, b_head, outp);
}

// Round 2
// 4142.971 us; speedup vs baseline: 2.7003x; 2.7003x over previous
//
#include <hip/hip_runtime.h>
#include <cstddef>

typedef __attribute__((ext_vector_type(8))) short bf16x8;
typedef __attribute__((ext_vector_type(4))) float f32x4;

#define Bc 4096
#define Tc 256
#define Hc 256
#define RB 64
#define HSTR 264          // padded bf16 row stride for h tiles
#define NSTEP 257
#define WFRAG_HEAD_OFF 786432

__device__ inline unsigned short f2bf(float f) {
    unsigned u = __float_as_uint(f);
    unsigned r = u + 0x7fffu + ((u >> 16) & 1u);
    return (unsigned short)(r >> 16);
}
__device__ inline float bf2f(unsigned short h) {
    return __uint_as_float(((unsigned)h) << 16);
}
__device__ inline float sigm(float x) { return __builtin_amdgcn_rcpf(1.f + __expf(-x)); }
__device__ inline float tanh_(float x) { return 1.f - 2.f * __builtin_amdgcn_rcpf(1.f + __expf(2.f * x)); }

// ---------------------------------------------------------------------------
// Build fragment-linear bf16 hi/lo copies of w_hh and w_head in ws.
// w_hh frag layout: [trio(16)][nc(3)][kt(8)]{hi[64][8], lo[64][8]} bf16
//   element (lane l, j): W[kt*32 + (l>>4)*8 + j][nc*256 + trio*16 + (l&15)]
// head frag at WFRAG_HEAD_OFF: [kt(8)]{hi[64][8], lo[64][8]},
//   col = l&15 (<2 real, else 0)
// ---------------------------------------------------------------------------
__global__ __launch_bounds__(256) void build_frags(
    const float* __restrict__ w_hh, const float* __restrict__ w_head,
    char* __restrict__ ws)
{
    int flat = blockIdx.x * 256 + threadIdx.x;
    if (blockIdx.x < 96) {
        int lane = flat & 63;
        int kt   = (flat >> 6) & 7;
        int nc   = (flat >> 9) % 3;
        int trio = flat / 1536;
        int c = nc * 256 + trio * 16 + (lane & 15);
        int kbase = kt * 32 + (lane >> 4) * 8;
        bf16x8 vh, vl;
        #pragma unroll
        for (int j = 0; j < 8; ++j) {
            float f = w_hh[(size_t)(kbase + j) * 768 + c];
            unsigned short h = f2bf(f);
            vh[j] = (short)h;
            vl[j] = (short)f2bf(f - bf2f(h));
        }
        size_t base = (size_t)((trio * 3 + nc) * 8 + kt) * 2048 + (size_t)lane * 16;
        *(bf16x8*)(ws + base)        = vh;
        *(bf16x8*)(ws + base + 1024) = vl;
    } else {
        int idx = flat - 96 * 256;       // 0..511
        int lane = idx & 63;
        int kt   = idx >> 6;
        int col  = lane & 15;
        int kbase = kt * 32 + (lane >> 4) * 8;
        bf16x8 vh, vl;
        #pragma unroll
        for (int j = 0; j < 8; ++j) {
            float f = (col < 2) ? w_head[(size_t)(kbase + j) * 2 + col] : 0.f;
            unsigned short h = f2bf(f);
            vh[j] = (short)h;
            vl[j] = (short)f2bf(f - bf2f(h));
        }
        size_t base = WFRAG_HEAD_OFF + (size_t)kt * 2048 + (size_t)lane * 16;
        *(bf16x8*)(ws + base)        = vh;
        *(bf16x8*)(ws + base + 1024) = vl;
    }
}

// ---------------------------------------------------------------------------
// GRU scan: 64 blocks x 512 threads (8 waves), 64 rows per block.
// Wave w owns trios {2w, 2w+1} (units [32w, 32w+32)) x all 4 M-tiles.
// gh = h @ w_hh via 3-pass split-bf16 MFMA (f32-class accuracy).
// Gate combine fully in-register (r/z/n of unit u land in the same lane).
// Head fused as extra MFMA tile on waves 0-3, one step delayed.
// ---------------------------------------------------------------------------
__global__ __launch_bounds__(512, 2) void gru_mfma(
    const float* __restrict__ cond, const float* __restrict__ ivf,
    const float* __restrict__ times,
    const float* __restrict__ w1, const float* __restrict__ b1,
    const float* __restrict__ w2, const float* __restrict__ b2,
    const float* __restrict__ w3, const float* __restrict__ b3,
    const float* __restrict__ wh0, const float* __restrict__ bh0,
    const float* __restrict__ w_ih, const float* __restrict__ b_ih,
    const float* __restrict__ b_hh, const float* __restrict__ b_head,
    const char* __restrict__ wfrag,
    float* __restrict__ out)
{
    __shared__ __align__(16) char smem[84224];
    unsigned short* h_hi = (unsigned short*)smem;            // [64][HSTR] bf16
    unsigned short* h_lo = (unsigned short*)(smem + 33792);  // [64][HSTR] bf16
    float* x_cur = (float*)(smem + 67584);                   // [64]
    float* embS  = (float*)(smem + 67840);                   // [64][64]
    float* s1 = (float*)smem;                                // alias [64][128]
    float* s2 = (float*)(smem + 32768);                      // alias [64][128]

    const int tid  = threadIdx.x;
    const int w    = tid >> 6;
    const int lane = tid & 63;
    const int l15  = lane & 15;
    const int q    = lane >> 4;
    const int row0 = blockIdx.x * RB;

    // ---- inline MLP + h0 (one-time) ----
    for (int o = tid; o < 64 * 128; o += 512) {
        int r = o >> 7, c = o & 127;
        float a = b1[c];
        #pragma unroll 4
        for (int k = 0; k < 64; ++k)
            a = fmaf(ivf[(size_t)(row0 + r) * 64 + k], w1[k * 128 + c], a);
        s1[o] = fmaxf(a, 0.f);
    }
    __syncthreads();
    for (int o = tid; o < 64 * 128; o += 512) {
        int r = o >> 7, c = o & 127;
        float a = b2[c];
        #pragma unroll 4
        for (int k = 0; k < 128; ++k)
            a = fmaf(s1[r * 128 + k], w2[k * 128 + c], a);
        s2[o] = fmaxf(a, 0.f);
    }
    __syncthreads();
    for (int o = tid; o < 64 * 64; o += 512) {
        int r = o >> 6, c = o & 63;
        float a = b3[c];
        #pragma unroll 4
        for (int k = 0; k < 128; ++k)
            a = fmaf(s2[r * 128 + k], w3[k * 64 + c], a);
        embS[o] = a;
    }
    __syncthreads();
    for (int o = tid; o < 64 * 256; o += 512) {
        int r = o >> 8, c = o & 255;
        float a = bh0[c];
        #pragma unroll 4
        for (int k = 0; k < 128; ++k)
            a = fmaf(cond[(size_t)(row0 + r) * 128 + k], wh0[k * 256 + c], a);
        #pragma unroll 4
        for (int k = 0; k < 64; ++k)
            a = fmaf(embS[r * 64 + k], wh0[(128 + k) * 256 + c], a);
        float h = tanh_(a);
        unsigned short hh = f2bf(h);
        h_hi[r * HSTR + c] = hh;
        h_lo[r * HSTR + c] = f2bf(h - bf2f(hh));
    }
    __syncthreads();

    // ---- per-lane constants + h_old registers ----
    int u[2]; float wiR[2], wiZ[2], wiN[2], bR[2], bZ[2], biN[2], bhN[2];
    float hold[2][4][4];
    #pragma unroll
    for (int p = 0; p < 2; ++p) {
        int uu = (2 * w + p) * 16 + l15;
        u[p] = uu;
        wiR[p] = w_ih[uu]; wiZ[p] = w_ih[256 + uu]; wiN[p] = w_ih[512 + uu];
        bR[p]  = b_ih[uu] + b_hh[uu];
        bZ[p]  = b_ih[256 + uu] + b_hh[256 + uu];
        biN[p] = b_ih[512 + uu];
        bhN[p] = b_hh[512 + uu];
        #pragma unroll
        for (int mt = 0; mt < 4; ++mt)
            #pragma unroll
            for (int j = 0; j < 4; ++j) {
                int m = mt * 16 + q * 4 + j;
                hold[p][mt][j] = bf2f(h_hi[m * HSTR + uu]) + bf2f(h_lo[m * HSTR + uu]);
            }
    }
    const float bheadLane = (l15 == 0) ? b_head[0] : ((l15 == 1) ? b_head[1] : 0.f);

    const char* wf_base[2][3];
    #pragma unroll
    for (int p = 0; p < 2; ++p)
        #pragma unroll
        for (int nc = 0; nc < 3; ++nc)
            wf_base[p][nc] = wfrag + (size_t)(((2 * w + p) * 3 + nc) * 8) * 2048
                                   + (size_t)lane * 16;
    const char* wf_head = wfrag + WFRAG_HEAD_OFF + (size_t)lane * 16;

    // ---- 257 GRU steps + 1 head-only epilogue ----
    for (int i = 0; i <= NSTEP; ++i) {
        const bool doGh   = (i < NSTEP);
        const bool doHead = (i >= 1);

        if (doGh && tid < 64) {
            float x = 0.f;
            if (i >= 1) {
                float a = times[(size_t)(row0 + tid) * Tc + (i - 1)];
                float b = (i >= 2) ? times[(size_t)(row0 + tid) * Tc + (i - 2)] : 0.f;
                x = a - b;
            }
            x_cur[tid] = x;
        }

        f32x4 aR[2][4], aZ[2][4], aN[2][4];
        #pragma unroll
        for (int p = 0; p < 2; ++p)
            #pragma unroll
            for (int mt = 0; mt < 4; ++mt) {
                aR[p][mt] = (f32x4){bR[p], bR[p], bR[p], bR[p]};
                aZ[p][mt] = (f32x4){bZ[p], bZ[p], bZ[p], bZ[p]};
                aN[p][mt] = (f32x4){bhN[p], bhN[p], bhN[p], bhN[p]};
            }
        f32x4 aH = (f32x4){bheadLane, bheadLane, bheadLane, bheadLane};

        const int abase = q * 8;

#define GH_NC(NC, ACC)                                                           \
        {                                                                        \
            bf16x8 Bhi = *(const bf16x8*)(wf_base[p][NC] + kt * 2048);           \
            bf16x8 Blo = *(const bf16x8*)(wf_base[p][NC] + kt * 2048 + 1024);    \
            _Pragma("unroll")                                                    \
            for (int mt = 0; mt < 4; ++mt) {                                     \
                ACC[p][mt] = __builtin_amdgcn_mfma_f32_16x16x32_bf16(            \
                    Ahi[mt], Bhi, ACC[p][mt], 0, 0, 0);                          \
                ACC[p][mt] = __builtin_amdgcn_mfma_f32_16x16x32_bf16(            \
                    Alo[mt], Bhi, ACC[p][mt], 0, 0, 0);                          \
                ACC[p][mt] = __builtin_amdgcn_mfma_f32_16x16x32_bf16(            \
                    Ahi[mt], Blo, ACC[p][mt], 0, 0, 0);                          \
            }                                                                    \
        }

        #pragma unroll 2
        for (int kt = 0; kt < 8; ++kt) {
            if (doGh) {
                bf16x8 Ahi[4], Alo[4];
                #pragma unroll
                for (int mt = 0; mt < 4; ++mt) {
                    int eo = (mt * 16 + l15) * HSTR + kt * 32 + abase;
                    Ahi[mt] = *(const bf16x8*)(h_hi + eo);
                    Alo[mt] = *(const bf16x8*)(h_lo + eo);
                }
                #pragma unroll
                for (int p = 0; p < 2; ++p) {
                    GH_NC(0, aR)
                    GH_NC(1, aZ)
                    GH_NC(2, aN)
                }
            }
            if (doHead && w < 4) {
                int eo = (w * 16 + l15) * HSTR + kt * 32 + abase;
                bf16x8 HAhi = *(const bf16x8*)(h_hi + eo);
                bf16x8 HAlo = *(const bf16x8*)(h_lo + eo);
                bf16x8 HBhi = *(const bf16x8*)(wf_head + kt * 2048);
                bf16x8 HBlo = *(const bf16x8*)(wf_head + kt * 2048 + 1024);
                aH = __builtin_amdgcn_mfma_f32_16x16x32_bf16(HAhi, HBhi, aH, 0, 0, 0);
                aH = __builtin_amdgcn_mfma_f32_16x16x32_bf16(HAlo, HBhi, aH, 0, 0, 0);
                aH = __builtin_amdgcn_mfma_f32_16x16x32_bf16(HAhi, HBlo, aH, 0, 0, 0);
            }
        }
#undef GH_NC

        if (doHead && w < 4 && l15 < 2) {
            size_t pbase = (size_t)l15 * ((size_t)Bc * NSTEP) + (size_t)(i - 1);
            #pragma unroll
            for (int j = 0; j < 4; ++j) {
                int m = w * 16 + q * 4 + j;
                out[pbase + (size_t)(row0 + m) * NSTEP] = aH[j];
            }
        }

        __syncthreads();   // A-reads of h done; x_cur visible

        if (doGh) {
            #pragma unroll
            for (int p = 0; p < 2; ++p)
                #pragma unroll
                for (int mt = 0; mt < 4; ++mt)
                    #pragma unroll
                    for (int j = 0; j < 4; ++j) {
                        int m = mt * 16 + q * 4 + j;
                        float x  = x_cur[m];
                        float rr = sigm(aR[p][mt][j] + x * wiR[p]);
                        float zz = sigm(aZ[p][mt][j] + x * wiZ[p]);
                        float nn = tanh_(fmaf(x, wiN[p], biN[p]) + rr * aN[p][mt][j]);
                        float hn = nn + zz * (hold[p][mt][j] - nn);
                        hold[p][mt][j] = hn;
                        unsigned short hh = f2bf(hn);
                        h_hi[m * HSTR + u[p]] = hh;
                        h_lo[m * HSTR + u[p]] = f2bf(hn - bf2f(hh));
                    }
        }
        __syncthreads();   // h_new visible for next iteration's A-reads
    }
}

// ---------------------------------------------------------------------------
extern "C" void kernel_launch(void* const* d_in, const int* in_sizes, int n_in,
                              void* d_out, int out_size, void* d_ws, size_t ws_size,
                              hipStream_t stream) {
    const float* cond   = (const float*)d_in[0];
    const float* ivf    = (const float*)d_in[1];
    const float* times  = (const float*)d_in[2];
    // d_in[3] = seq_lens (unused by reference)
    const float* w1     = (const float*)d_in[4];
    const float* b1     = (const float*)d_in[5];
    const float* w2     = (const float*)d_in[6];
    const float* b2     = (const float*)d_in[7];
    const float* w3     = (const float*)d_in[8];
    const float* b3     = (const float*)d_in[9];
    const float* wh0    = (const float*)d_in[10];
    const float* bh0    = (const float*)d_in[11];
    const float* w_ih   = (const float*)d_in[12];
    const float* b_ih   = (const float*)d_in[13];
    const float* w_hh   = (const float*)d_in[14];
    const float* b_hh   = (const float*)d_in[15];
    const float* w_head = (const float*)d_in[16];
    const float* b_head = (const float*)d_in[17];

    float* outp = (float*)d_out;
    char*  ws   = (char*)d_ws;

    build_frags<<<98, 256, 0, stream>>>(w_hh, w_head, ws);
    gru_mfma<<<64, 512, 0, stream>>>(cond, ivf, times,
                                     w1, b1, w2, b2, w3, b3, wh0, bh0,
                                     w_ih, b_ih, b_hh, b_head,
                                     (const char*)ws, outp);
}

// Round 3
// 1198.149 us; speedup vs baseline: 9.3370x; 3.4578x over previous
//
#include <hip/hip_runtime.h>
#include <cstddef>

typedef _Float16 f16x8 __attribute__((ext_vector_type(8)));
typedef float    f32x4 __attribute__((ext_vector_type(4)));

#define Bc 4096
#define Tc 256
#define NSTEP 257
#define RB 16               // rows per block
#define HSTR 264            // fp16 h-tile row stride (conflict-free b128 reads)
#define HEAD_OFF 393216     // byte offset of head frags in ws

__device__ inline float sigm(float x)  { return __builtin_amdgcn_rcpf(1.f + __expf(-x)); }
__device__ inline float tanh_(float x) { return 1.f - 2.f * __builtin_amdgcn_rcpf(1.f + __expf(2.f * x)); }

// ---------------------------------------------------------------------------
// Build fragment-linear fp16 copies of w_hh and w_head in ws.
// w_hh frag f = (trio*3+nc)*8 + kt, 1024 B each:
//   element (lane l, j) = W[kt*32 + (l>>4)*8 + j][nc*256 + trio*16 + (l&15)]
// head frags at HEAD_OFF, kt = 0..7: col = l&15 (<2 real, else 0)
// ---------------------------------------------------------------------------
__global__ __launch_bounds__(256) void build_frags(
    const float* __restrict__ w_hh, const float* __restrict__ w_head,
    _Float16* __restrict__ ws)
{
    int flat = blockIdx.x * 256 + threadIdx.x;
    if (blockIdx.x < 96) {
        int f    = flat >> 6;          // 0..383
        int lane = flat & 63;
        int kt   = f & 7;
        int nc   = (f >> 3) % 3;
        int trio = f / 24;
        int c     = nc * 256 + trio * 16 + (lane & 15);
        int kbase = kt * 32 + (lane >> 4) * 8;
        _Float16* dst = ws + (size_t)f * 512 + (size_t)lane * 8;
        #pragma unroll
        for (int j = 0; j < 8; ++j)
            dst[j] = (_Float16)w_hh[(size_t)(kbase + j) * 768 + c];
    } else {
        int idx = flat - 96 * 256;     // 0..511
        int kt   = idx >> 6;
        int lane = idx & 63;
        int col   = lane & 15;
        int kbase = kt * 32 + (lane >> 4) * 8;
        _Float16* dst = ws + HEAD_OFF / 2 + (size_t)kt * 512 + (size_t)lane * 8;
        #pragma unroll
        for (int j = 0; j < 8; ++j)
            dst[j] = (col < 2) ? (_Float16)w_head[(size_t)(kbase + j) * 2 + col]
                               : (_Float16)0.f;
    }
}

// ---------------------------------------------------------------------------
// GRU scan: 256 blocks x 512 threads (8 waves), 16 rows per block.
// Wave w owns trios {2w, 2w+1} (units [32w,32w+32)).
// All 48 B-frags (6 n-tiles x 8 k-tiles) live in registers for all 257 steps.
// h kept f32 in registers (recurrence exact); fp16 copy in LDS feeds MFMA A.
// Head fused on wave 0 (reuses A-frags), one step delayed.
// ---------------------------------------------------------------------------
__global__ __launch_bounds__(512, 2) void gru_mfma(
    const float* __restrict__ cond, const float* __restrict__ ivf,
    const float* __restrict__ times,
    const float* __restrict__ w1, const float* __restrict__ b1,
    const float* __restrict__ w2, const float* __restrict__ b2,
    const float* __restrict__ w3, const float* __restrict__ b3,
    const float* __restrict__ wh0, const float* __restrict__ bh0,
    const float* __restrict__ w_ih, const float* __restrict__ b_ih,
    const float* __restrict__ b_hh, const float* __restrict__ b_head,
    const _Float16* __restrict__ wfrag,
    float* __restrict__ out)
{
    __shared__ __align__(16) _Float16 h16[RB * HSTR];     // 8448 B
    __shared__ float  xs[RB * NSTEP];                     // 16448 B
    __shared__ __align__(16) _Float16 headB[4096];        // 8192 B
    __shared__ float  mlp1[RB * 128];
    __shared__ float  mlp2[RB * 128];
    __shared__ float  embS[RB * 64];
    __shared__ float  h0f[RB * 256];

    const int tid  = threadIdx.x;
    const int w    = tid >> 6;
    const int lane = tid & 63;
    const int l15  = lane & 15;
    const int q    = lane >> 4;
    const int row0 = blockIdx.x * RB;

    // ---- preamble: MLP + h0 for the block's 16 rows ----
    for (int o = tid; o < RB * 128; o += 512) {
        int r = o >> 7, c = o & 127;
        float a = b1[c];
        #pragma unroll 4
        for (int k = 0; k < 64; ++k)
            a = fmaf(ivf[(size_t)(row0 + r) * 64 + k], w1[k * 128 + c], a);
        mlp1[o] = fmaxf(a, 0.f);
    }
    __syncthreads();
    for (int o = tid; o < RB * 128; o += 512) {
        int r = o >> 7, c = o & 127;
        float a = b2[c];
        #pragma unroll 4
        for (int k = 0; k < 128; ++k)
            a = fmaf(mlp1[r * 128 + k], w2[k * 128 + c], a);
        mlp2[o] = fmaxf(a, 0.f);
    }
    __syncthreads();
    for (int o = tid; o < RB * 64; o += 512) {
        int r = o >> 6, c = o & 63;
        float a = b3[c];
        #pragma unroll 4
        for (int k = 0; k < 128; ++k)
            a = fmaf(mlp2[r * 128 + k], w3[k * 64 + c], a);
        embS[o] = a;
    }
    __syncthreads();
    for (int o = tid; o < RB * 256; o += 512) {
        int r = o >> 8, c = o & 255;
        float a = bh0[c];
        #pragma unroll 4
        for (int k = 0; k < 128; ++k)
            a = fmaf(cond[(size_t)(row0 + r) * 128 + k], wh0[k * 256 + c], a);
        #pragma unroll 4
        for (int k = 0; k < 64; ++k)
            a = fmaf(embS[r * 64 + k], wh0[(128 + k) * 256 + c], a);
        h0f[o] = tanh_(a);
    }
    __syncthreads();

    // fp16 h tile, xs table, head-B staging
    for (int o = tid; o < RB * 256; o += 512) {
        int r = o >> 8, c = o & 255;
        h16[r * HSTR + c] = (_Float16)h0f[o];
    }
    for (int o = tid; o < RB * NSTEP; o += 512) {
        int r = o / NSTEP, ii = o - r * NSTEP;
        float x = 0.f;
        if (ii >= 1) {
            float a = times[(size_t)(row0 + r) * Tc + (ii - 1)];
            float b = (ii >= 2) ? times[(size_t)(row0 + r) * Tc + (ii - 2)] : 0.f;
            x = a - b;
        }
        xs[o] = x;
    }
    {
        const float4* src = (const float4*)(wfrag + HEAD_OFF / 2);
        ((float4*)headB)[tid] = src[tid];
    }

    // ---- per-lane constants, register-resident weights, h state ----
    int u0 = (2 * w) * 16 + l15, u1 = (2 * w + 1) * 16 + l15;
    float wiR[2] = { w_ih[u0],       w_ih[u1] };
    float wiZ[2] = { w_ih[256 + u0], w_ih[256 + u1] };
    float wiN[2] = { w_ih[512 + u0], w_ih[512 + u1] };
    float bR [2] = { b_ih[u0] + b_hh[u0],             b_ih[u1] + b_hh[u1] };
    float bZ [2] = { b_ih[256 + u0] + b_hh[256 + u0], b_ih[256 + u1] + b_hh[256 + u1] };
    float biN[2] = { b_ih[512 + u0],                  b_ih[512 + u1] };
    float bhN[2] = { b_hh[512 + u0],                  b_hh[512 + u1] };
    const float bheadLane = (l15 == 0) ? b_head[0] : ((l15 == 1) ? b_head[1] : 0.f);

    f16x8 Bf[2][3][8];
    #pragma unroll
    for (int p = 0; p < 2; ++p)
        #pragma unroll
        for (int nc = 0; nc < 3; ++nc)
            #pragma unroll
            for (int kt = 0; kt < 8; ++kt)
                Bf[p][nc][kt] = *(const f16x8*)(wfrag
                    + (size_t)(((2 * w + p) * 3 + nc) * 8 + kt) * 512
                    + (size_t)lane * 8);

    __syncthreads();

    float hold[2][4];
    #pragma unroll
    for (int p = 0; p < 2; ++p)
        #pragma unroll
        for (int j = 0; j < 4; ++j)
            hold[p][j] = h0f[(q * 4 + j) * 256 + (p ? u1 : u0)];

    // ---- 257 GRU steps + 1 head-only epilogue ----
    for (int i = 0; i <= NSTEP; ++i) {
        const bool doGh   = (i < NSTEP);
        const bool doHead = (i >= 1) && (w == 0);

        f32x4 aR[2], aZ[2], aN[2];
        #pragma unroll
        for (int p = 0; p < 2; ++p) {
            aR[p] = (f32x4){bR[p], bR[p], bR[p], bR[p]};
            aZ[p] = (f32x4){bZ[p], bZ[p], bZ[p], bZ[p]};
            aN[p] = (f32x4){bhN[p], bhN[p], bhN[p], bhN[p]};
        }
        f32x4 aH = (f32x4){bheadLane, bheadLane, bheadLane, bheadLane};

        #pragma unroll
        for (int kt = 0; kt < 8; ++kt) {
            f16x8 Af = *(const f16x8*)(h16 + l15 * HSTR + kt * 32 + q * 8);
            if (doGh) {
                #pragma unroll
                for (int p = 0; p < 2; ++p) {
                    aR[p] = __builtin_amdgcn_mfma_f32_16x16x32_f16(Af, Bf[p][0][kt], aR[p], 0, 0, 0);
                    aZ[p] = __builtin_amdgcn_mfma_f32_16x16x32_f16(Af, Bf[p][1][kt], aZ[p], 0, 0, 0);
                    aN[p] = __builtin_amdgcn_mfma_f32_16x16x32_f16(Af, Bf[p][2][kt], aN[p], 0, 0, 0);
                }
            }
            if (doHead) {
                f16x8 Bh = *(const f16x8*)(headB + kt * 512 + lane * 8);
                aH = __builtin_amdgcn_mfma_f32_16x16x32_f16(Af, Bh, aH, 0, 0, 0);
            }
        }

        if (doHead && l15 < 2) {
            size_t pbase = (size_t)l15 * ((size_t)Bc * NSTEP) + (size_t)(i - 1);
            #pragma unroll
            for (int j = 0; j < 4; ++j)
                out[pbase + (size_t)(row0 + q * 4 + j) * NSTEP] = aH[j];
        }

        __syncthreads();   // all A-reads of h_i complete

        if (doGh) {
            #pragma unroll
            for (int p = 0; p < 2; ++p) {
                const int u = p ? u1 : u0;
                #pragma unroll
                for (int j = 0; j < 4; ++j) {
                    const int m = q * 4 + j;
                    const float x  = xs[m * NSTEP + i];
                    const float rr = sigm(aR[p][j] + x * wiR[p]);
                    const float zz = sigm(aZ[p][j] + x * wiZ[p]);
                    const float nn = tanh_(fmaf(x, wiN[p], biN[p]) + rr * aN[p][j]);
                    const float hn = nn + zz * (hold[p][j] - nn);
                    hold[p][j] = hn;
                    h16[m * HSTR + u] = (_Float16)hn;
                }
            }
        }
        __syncthreads();   // h_{i+1} visible for next step's A-reads
    }
}

// ---------------------------------------------------------------------------
extern "C" void kernel_launch(void* const* d_in, const int* in_sizes, int n_in,
                              void* d_out, int out_size, void* d_ws, size_t ws_size,
                              hipStream_t stream) {
    const float* cond   = (const float*)d_in[0];
    const float* ivf    = (const float*)d_in[1];
    const float* times  = (const float*)d_in[2];
    // d_in[3] = seq_lens (unused by reference)
    const float* w1     = (const float*)d_in[4];
    const float* b1     = (const float*)d_in[5];
    const float* w2     = (const float*)d_in[6];
    const float* b2     = (const float*)d_in[7];
    const float* w3     = (const float*)d_in[8];
    const float* b3     = (const float*)d_in[9];
    const float* wh0    = (const float*)d_in[10];
    const float* bh0    = (const float*)d_in[11];
    const float* w_ih   = (const float*)d_in[12];
    const float* b_ih   = (const float*)d_in[13];
    const float* w_hh   = (const float*)d_in[14];
    const float* b_hh   = (const float*)d_in[15];
    const float* w_head = (const float*)d_in[16];
    const float* b_head = (const float*)d_in[17];

    float*    outp = (float*)d_out;
    _Float16* ws   = (_Float16*)d_ws;

    build_frags<<<98, 256, 0, stream>>>(w_hh, w_head, ws);
    gru_mfma<<<Bc / RB, 512, 0, stream>>>(cond, ivf, times,
                                          w1, b1, w2, b2, w3, b3, wh0, bh0,
                                          w_ih, b_ih, b_hh, b_head,
                                          (const _Float16*)ws, outp);
}

// Round 4
// 718.246 us; speedup vs baseline: 15.5757x; 1.6682x over previous
//
#include <hip/hip_runtime.h>
#include <cstddef>

typedef _Float16 f16x8 __attribute__((ext_vector_type(8)));
typedef float    f32x4 __attribute__((ext_vector_type(4)));

#define Bc 4096
#define Tc 256
#define NSTEP 257
#define RB 16               // rows per block
#define HSTR 264            // fp16 h-tile row stride
#define HEAD_OFF 393216     // byte offset of head frags in ws

__device__ inline float sigm(float x)  { return __builtin_amdgcn_rcpf(1.f + __expf(-x)); }
__device__ inline float tanh_(float x) { return 1.f - 2.f * __builtin_amdgcn_rcpf(1.f + __expf(2.f * x)); }

// ---------------------------------------------------------------------------
// Build fragment-linear fp16 copies of w_hh and w_head in ws.
// w_hh frag f = (trio*3+nc)*8 + kt, 1024 B each:
//   element (lane l, j) = W[kt*32 + (l>>4)*8 + j][nc*256 + trio*16 + (l&15)]
// head frags at HEAD_OFF, kt = 0..7: col = l&15 (<2 real, else 0)
// ---------------------------------------------------------------------------
__global__ __launch_bounds__(256) void build_frags(
    const float* __restrict__ w_hh, const float* __restrict__ w_head,
    _Float16* __restrict__ ws)
{
    int flat = blockIdx.x * 256 + threadIdx.x;
    if (blockIdx.x < 96) {
        int f    = flat >> 6;          // 0..383
        int lane = flat & 63;
        int kt   = f & 7;
        int nc   = (f >> 3) % 3;
        int trio = f / 24;
        int c     = nc * 256 + trio * 16 + (lane & 15);
        int kbase = kt * 32 + (lane >> 4) * 8;
        _Float16* dst = ws + (size_t)f * 512 + (size_t)lane * 8;
        #pragma unroll
        for (int j = 0; j < 8; ++j)
            dst[j] = (_Float16)w_hh[(size_t)(kbase + j) * 768 + c];
    } else {
        int idx = flat - 96 * 256;     // 0..511
        int kt   = idx >> 6;
        int lane = idx & 63;
        int col   = lane & 15;
        int kbase = kt * 32 + (lane >> 4) * 8;
        _Float16* dst = ws + HEAD_OFF / 2 + (size_t)kt * 512 + (size_t)lane * 8;
        #pragma unroll
        for (int j = 0; j < 8; ++j)
            dst[j] = (col < 2) ? (_Float16)w_head[(size_t)(kbase + j) * 2 + col]
                               : (_Float16)0.f;
    }
}

// ---------------------------------------------------------------------------
// GRU scan: 256 blocks x 512 threads (8 waves), 16 rows per block.
// Wave w owns units [32w, 32w+32). All 48 B-frags pinned in registers for all
// 257 steps (amdgpu_waves_per_eu(2,2) -> 256-VGPR budget, no spill).
// Gate constants live in LDS (saves ~14 VGPRs). Output staged in LDS,
// flushed as full 64-B lines every 16 steps.
// ---------------------------------------------------------------------------
__global__ __attribute__((amdgpu_waves_per_eu(2, 2))) __launch_bounds__(512)
void gru_mfma(
    const float* __restrict__ cond, const float* __restrict__ ivf,
    const float* __restrict__ times,
    const float* __restrict__ w1, const float* __restrict__ b1,
    const float* __restrict__ w2, const float* __restrict__ b2,
    const float* __restrict__ w3, const float* __restrict__ b3,
    const float* __restrict__ wh0, const float* __restrict__ bh0,
    const float* __restrict__ w_ih, const float* __restrict__ b_ih,
    const float* __restrict__ b_hh, const float* __restrict__ b_head,
    const _Float16* __restrict__ wfrag,
    float* __restrict__ out)
{
    __shared__ __align__(16) _Float16 h16[RB * HSTR];     // 8448 B
    __shared__ float  xs[RB * NSTEP];                     // 16448 B
    __shared__ __align__(16) _Float16 headB[4096];        // 8192 B
    __shared__ float  gateC[256 * 8];                     // 8192 B
    __shared__ float  outbuf[2][RB][16];                  // 2048 B
    __shared__ float  bh2[2];
    __shared__ float  mlp1[RB * 128];
    __shared__ float  mlp2[RB * 128];
    __shared__ float  embS[RB * 64];
    __shared__ float  h0f[RB * 256];

    const int tid  = threadIdx.x;
    const int w    = tid >> 6;
    const int lane = tid & 63;
    const int l15  = lane & 15;
    const int q    = lane >> 4;
    const int row0 = blockIdx.x * RB;

    // ---- preamble: MLP + h0 for the block's 16 rows ----
    for (int o = tid; o < RB * 128; o += 512) {
        int r = o >> 7, c = o & 127;
        float a = b1[c];
        #pragma unroll 4
        for (int k = 0; k < 64; ++k)
            a = fmaf(ivf[(size_t)(row0 + r) * 64 + k], w1[k * 128 + c], a);
        mlp1[o] = fmaxf(a, 0.f);
    }
    __syncthreads();
    for (int o = tid; o < RB * 128; o += 512) {
        int r = o >> 7, c = o & 127;
        float a = b2[c];
        #pragma unroll 4
        for (int k = 0; k < 128; ++k)
            a = fmaf(mlp1[r * 128 + k], w2[k * 128 + c], a);
        mlp2[o] = fmaxf(a, 0.f);
    }
    __syncthreads();
    for (int o = tid; o < RB * 64; o += 512) {
        int r = o >> 6, c = o & 63;
        float a = b3[c];
        #pragma unroll 4
        for (int k = 0; k < 128; ++k)
            a = fmaf(mlp2[r * 128 + k], w3[k * 64 + c], a);
        embS[o] = a;
    }
    __syncthreads();
    for (int o = tid; o < RB * 256; o += 512) {
        int r = o >> 8, c = o & 255;
        float a = bh0[c];
        #pragma unroll 4
        for (int k = 0; k < 128; ++k)
            a = fmaf(cond[(size_t)(row0 + r) * 128 + k], wh0[k * 256 + c], a);
        #pragma unroll 4
        for (int k = 0; k < 64; ++k)
            a = fmaf(embS[r * 64 + k], wh0[(128 + k) * 256 + c], a);
        h0f[o] = tanh_(a);
    }
    __syncthreads();

    // fp16 h tile, xs table, head-B staging, gate-constant table
    for (int o = tid; o < RB * 256; o += 512) {
        int r = o >> 8, c = o & 255;
        h16[r * HSTR + c] = (_Float16)h0f[o];
    }
    for (int o = tid; o < RB * NSTEP; o += 512) {
        int r = o / NSTEP, ii = o - r * NSTEP;
        float x = 0.f;
        if (ii >= 1) {
            float a = times[(size_t)(row0 + r) * Tc + (ii - 1)];
            float b = (ii >= 2) ? times[(size_t)(row0 + r) * Tc + (ii - 2)] : 0.f;
            x = a - b;
        }
        xs[o] = x;
    }
    {
        const float4* src = (const float4*)(wfrag + HEAD_OFF / 2);
        ((float4*)headB)[tid] = src[tid];
    }
    for (int uu = tid; uu < 256; uu += 512) {
        gateC[uu * 8 + 0] = w_ih[uu];
        gateC[uu * 8 + 1] = w_ih[256 + uu];
        gateC[uu * 8 + 2] = w_ih[512 + uu];
        gateC[uu * 8 + 3] = b_ih[uu] + b_hh[uu];
        gateC[uu * 8 + 4] = b_ih[256 + uu] + b_hh[256 + uu];
        gateC[uu * 8 + 5] = b_ih[512 + uu];
        gateC[uu * 8 + 6] = b_hh[512 + uu];
        gateC[uu * 8 + 7] = 0.f;
    }
    if (tid < 2) bh2[tid] = b_head[tid];

    // ---- register-resident weight fragments: 48 x f16x8 = 192 VGPR ----
    const int u0 = w * 32 + l15;
    const int u1 = u0 + 16;

    f16x8 Bf[2][3][8];
    #pragma unroll
    for (int p = 0; p < 2; ++p)
        #pragma unroll
        for (int nc = 0; nc < 3; ++nc)
            #pragma unroll
            for (int kt = 0; kt < 8; ++kt)
                Bf[p][nc][kt] = *(const f16x8*)(wfrag
                    + (size_t)(((2 * w + p) * 3 + nc) * 8 + kt) * 512
                    + (size_t)lane * 8);

    __syncthreads();

    float hold[2][4];
    #pragma unroll
    for (int p = 0; p < 2; ++p)
        #pragma unroll
        for (int j = 0; j < 4; ++j)
            hold[p][j] = h0f[(q * 4 + j) * 256 + (p ? u1 : u0)];

    // ---- 257 GRU steps + 1 head-only epilogue ----
    for (int i = 0; i <= NSTEP; ++i) {
        const bool doGh   = (i < NSTEP);
        const bool doHead = (i >= 1) && (w == 0);

        f32x4 aR[2], aZ[2], aN[2];
        #pragma unroll
        for (int p = 0; p < 2; ++p) {
            aR[p] = (f32x4){0.f, 0.f, 0.f, 0.f};
            aZ[p] = (f32x4){0.f, 0.f, 0.f, 0.f};
            aN[p] = (f32x4){0.f, 0.f, 0.f, 0.f};
        }
        f32x4 aH = (f32x4){0.f, 0.f, 0.f, 0.f};

        #pragma unroll
        for (int kt = 0; kt < 8; ++kt) {
            f16x8 Af = *(const f16x8*)(h16 + l15 * HSTR + kt * 32 + q * 8);
            if (doGh) {
                #pragma unroll
                for (int p = 0; p < 2; ++p) {
                    aR[p] = __builtin_amdgcn_mfma_f32_16x16x32_f16(Af, Bf[p][0][kt], aR[p], 0, 0, 0);
                    aZ[p] = __builtin_amdgcn_mfma_f32_16x16x32_f16(Af, Bf[p][1][kt], aZ[p], 0, 0, 0);
                    aN[p] = __builtin_amdgcn_mfma_f32_16x16x32_f16(Af, Bf[p][2][kt], aN[p], 0, 0, 0);
                }
            }
            if (doHead) {
                f16x8 Bh = *(const f16x8*)(headB + kt * 512 + lane * 8);
                aH = __builtin_amdgcn_mfma_f32_16x16x32_f16(Af, Bh, aH, 0, 0, 0);
            }
        }

        if (doHead && l15 < 2) {
            const int o = i - 1;
            #pragma unroll
            for (int j = 0; j < 4; ++j)
                outbuf[l15][q * 4 + j][o & 15] = aH[j];
        }

        __syncthreads();   // A-reads of h_i done; outbuf slot visible

        // coalesced output flush every 16 steps (+ final partial)
        if (i >= 1) {
            const int o = i - 1;
            if (((o & 15) == 15) || (o == NSTEP - 1)) {
                const int cnt   = (o & 15) + 1;
                const int obase = o & ~15;
                const int e     = tid & 15;
                const int row   = (tid >> 4) & 15;
                const int plane = tid >> 8;
                if (e < cnt)
                    out[(size_t)plane * ((size_t)Bc * NSTEP)
                        + (size_t)(row0 + row) * NSTEP + obase + e]
                        = outbuf[plane][row][e] + bh2[plane];
            }
        }

        if (doGh) {
            #pragma unroll
            for (int p = 0; p < 2; ++p) {
                const int u = p ? u1 : u0;
                const f32x4 g0 = *(const f32x4*)(gateC + u * 8);      // wiR,wiZ,wiN,bR
                const f32x4 g1 = *(const f32x4*)(gateC + u * 8 + 4);  // bZ,biN,bhN,pad
                #pragma unroll
                for (int j = 0; j < 4; ++j) {
                    const int m = q * 4 + j;
                    const float x  = xs[m * NSTEP + i];
                    const float rr = sigm(fmaf(x, g0[0], g0[3]) + aR[p][j]);
                    const float zz = sigm(fmaf(x, g0[1], g1[0]) + aZ[p][j]);
                    const float nn = tanh_(fmaf(x, g0[2], g1[1]) + rr * (aN[p][j] + g1[2]));
                    const float hn = nn + zz * (hold[p][j] - nn);
                    hold[p][j] = hn;
                    h16[m * HSTR + u] = (_Float16)hn;
                }
            }
        }
        __syncthreads();   // h_{i+1} visible for next step's A-reads
    }
}

// ---------------------------------------------------------------------------
extern "C" void kernel_launch(void* const* d_in, const int* in_sizes, int n_in,
                              void* d_out, int out_size, void* d_ws, size_t ws_size,
                              hipStream_t stream) {
    const float* cond   = (const float*)d_in[0];
    const float* ivf    = (const float*)d_in[1];
    const float* times  = (const float*)d_in[2];
    // d_in[3] = seq_lens (unused by reference)
    const float* w1     = (const float*)d_in[4];
    const float* b1     = (const float*)d_in[5];
    const float* w2     = (const float*)d_in[6];
    const float* b2     = (const float*)d_in[7];
    const float* w3     = (const float*)d_in[8];
    const float* b3     = (const float*)d_in[9];
    const float* wh0    = (const float*)d_in[10];
    const float* bh0    = (const float*)d_in[11];
    const float* w_ih   = (const float*)d_in[12];
    const float* b_ih   = (const float*)d_in[13];
    const float* w_hh   = (const float*)d_in[14];
    const float* b_hh   = (const float*)d_in[15];
    const float* w_head = (const float*)d_in[16];
    const float* b_head = (const float*)d_in[17];

    float*    outp = (float*)d_out;
    _Float16* ws   = (_Float16*)d_ws;

    build_frags<<<98, 256, 0, stream>>>(w_hh, w_head, ws);
    gru_mfma<<<Bc / RB, 512, 0, stream>>>(cond, ivf, times,
                                          w1, b1, w2, b2, w3, b3, wh0, bh0,
                                          w_ih, b_ih, b_hh, b_head,
                                          (const _Float16*)ws, outp);
}